// Round 14
// baseline (461.447 us; speedup 1.0000x reference)
//
#include <hip/hip_runtime.h>
#include <hip/hip_fp16.h>
#include <hip/hip_cooperative_groups.h>

namespace cg = cooperative_groups;

// GCN on MI355X — ONE cooperative build kernel (+agg, +out) = 3 launches.
//
// Algebra: layer2 collapses through the linear head:
//   out = segsum((relu(c1) . (W2@Wl) * ns)[src], dst)*nd + (b2@Wl + bl)
// so only a per-node SCALAR feeds the second aggregation.
//
// R13: tail (~145us) proved invariant under traffic optimizations (R6-R12)
// => inter-dispatch overhead (~6us x 12 stages). Collapse cnt/scan/bucket/
// hist/reduce_norm/scan-chain/fill/gemm into ONE cooperative kernel with 5
// grid.sync()s. Hist re-packed to 16 half-ranges (6250 bins = 25KB LDS) so
// the coop kernel is guaranteed co-resident at grid=512, 2 blocks/CU.

#define WAVE 64
#define NRANGE 8
#define CB 1024
#define GRID 512
#define CHK 32            // hist chunks
#define RB (CB / CHK)     // bucket chunks per hist chunk = 32

typedef _Float16 f16x8 __attribute__((ext_vector_type(8)));
typedef float f32x4 __attribute__((ext_vector_type(4)));

__global__ __launch_bounds__(256, 2) void k_build(
    const int* __restrict__ src, const int* __restrict__ dst,
    const float* __restrict__ x,
    const float* __restrict__ W1, const float* __restrict__ W2,
    const float* __restrict__ b2, const float* __restrict__ Wl,
    const float* __restrict__ bl,
    unsigned* cnt, unsigned* segBase, uint2* ebuf,
    unsigned* partial_s, unsigned* partial_d,
    float* norm_s, float* norm_d, unsigned* deg_d,
    unsigned* partial, unsigned* blockoff, unsigned* offsets,
    unsigned* csr, _Float16* wt, float* w2l, float* c0, __half* h1h,
    int E, int N, int rngB, int hb, int chunkEb, int chunkE,
    int NB, int ntiles)
{
    extern __shared__ unsigned lds[];
    cg::grid_group grid = cg::this_grid();
    const int bid = blockIdx.x;
    const int tid = threadIdx.x;
    const int lane = tid & 63;

    // ================= PH0: cnt chunks + prep + hist =================
    for (int c = bid; c < CB; c += GRID) {
        if (tid < NRANGE) lds[tid] = 0u;
        __syncthreads();
        const int beg = c * chunkEb, end = min(beg + chunkEb, E);
        unsigned pc[NRANGE] = {};
        for (int i = beg + tid; i < end; i += 256) {
            int r = dst[i] / rngB;
#pragma unroll
            for (int rr = 0; rr < NRANGE; ++rr) pc[rr] += (r == rr);
        }
#pragma unroll
        for (int rr = 0; rr < NRANGE; ++rr) {
            unsigned v = pc[rr];
#pragma unroll
            for (int off = 32; off; off >>= 1) v += __shfl_xor((int)v, off);
            if (lane == 0 && v) atomicAdd(&lds[rr], v);
        }
        __syncthreads();
        if (tid < NRANGE) cnt[tid * CB + c] = lds[tid];
        __syncthreads();
    }
    if (bid == GRID - 1) {                       // prep: wt, w2l, c0
        for (int i = 0; i < 32; ++i) {
            int e = i * 256 + tid;
            int k = e >> 6, n = e & 63;
            wt[n * 128 + k] = (_Float16)W1[e];
        }
        if (tid < 64) {
            float acc = 0.f;
#pragma unroll
            for (int j = 0; j < 32; ++j) acc += W2[tid * 32 + j] * Wl[j];
            w2l[tid] = acc;
        }
        if (tid == 0) {
            float s = 0.f;
#pragma unroll
            for (int j = 0; j < 32; ++j) s += b2[j] * Wl[j];
            *c0 = s + bl[0];
        }
    }
    if (bid < 256) {                              // hist: 2 arrays x 4 quads x CHK
        const int arr = bid >> 7;
        const int hq  = (bid >> 5) & 3;
        const int c   = bid & 31;
        const int lo  = hq * 4 * hb;
        const int span = 4 * hb;
        const int* nodes = arr ? dst : src;
        unsigned* po = (arr ? partial_d : partial_s) + (size_t)(hq * CHK + c) * hb;
        for (int b = tid; b < hb; b += 256) lds[b] = 0u;
        __syncthreads();
        const int beg = c * chunkE, end = min(beg + chunkE, E);
        const int n4 = (end - beg) >> 2;          // beg 4-aligned (chunkE%4==0)
        const int4* p = (const int4*)(nodes + beg);
        for (int j = tid; j < n4; j += 256) {
            int4 v = p[j];
#pragma unroll
            for (int k = 0; k < 4; ++k) {
                int a = (&v.x)[k] - lo;
                if ((unsigned)a < (unsigned)span) {
                    int jj = a / hb;
                    int b = a - jj * hb;
                    atomicAdd(&lds[b], 1u << (jj << 3));
                }
            }
        }
        for (int j2 = beg + (n4 << 2) + tid; j2 < end; j2 += 256) {
            int a = nodes[j2] - lo;
            if ((unsigned)a < (unsigned)span) {
                int jj = a / hb;
                int b = a - jj * hb;
                atomicAdd(&lds[b], 1u << (jj << 3));
            }
        }
        __syncthreads();
        for (int b = tid; b < hb; b += 256) po[b] = lds[b];
    }
    grid.sync();

    // ================= PH1: scancnt (block 0) || reduce_norm =================
    if (bid == 0) {
        const int PER = (NRANGE * CB) / 256;      // 32
        unsigned loc[PER];
        unsigned sum = 0;
#pragma unroll
        for (int j = 0; j < PER; ++j) { loc[j] = sum; sum += cnt[tid * PER + j]; }
        lds[tid] = sum;
        __syncthreads();
        for (int off = 1; off < 256; off <<= 1) {
            unsigned a = (tid >= off) ? lds[tid - off] : 0u;
            __syncthreads();
            lds[tid] += a;
            __syncthreads();
        }
        unsigned base = lds[tid] - sum;
#pragma unroll
        for (int j = 0; j < PER; ++j) segBase[tid * PER + j] = base + loc[j];
        if (tid == 255) segBase[NRANGE * CB] = lds[255];
    } else {
        int t = (bid - 1) * 256 + tid;            // 4*hb tasks
        if (t < 4 * hb) {
            int hq = t / hb, b = t - hq * hb;
            size_t base = (size_t)(hq * CHK) * hb + b;
            unsigned ds = 0;
            for (int c = 0; c < CHK; ++c) ds += partial_s[base + (size_t)c * hb];
            unsigned run = 0;
            for (int c = 0; c < CHK; ++c) {
                size_t ix = base + (size_t)c * hb;
                unsigned v = partial_d[ix];
                partial_d[ix] = run;              // packed exclusive prefix
                run += v;
            }
#pragma unroll
            for (int j = 0; j < 4; ++j) {
                int n = hq * 4 * hb + j * hb + b;
                if (n < N) {
                    unsigned d0 = (ds >> (8 * j)) & 0xffu;
                    unsigned d1 = (run >> (8 * j)) & 0xffu;
                    deg_d[n] = d1;
                    norm_s[n] = d0 ? rsqrtf((float)d0) : 0.0f;
                    norm_d[n] = d1 ? rsqrtf((float)d1) : 0.0f;
                }
            }
        }
    }
    grid.sync();

    // ================= PH2: bucket + blocksum + gemm =================
    for (int c = bid; c < CB; c += GRID) {
        if (tid < NRANGE) lds[tid] = 0u;          // append cursors
        __syncthreads();
        unsigned sb[NRANGE];
#pragma unroll
        for (int r = 0; r < NRANGE; ++r) sb[r] = segBase[r * CB + c];
        const int beg = c * chunkEb, end = min(beg + chunkEb, E);
        for (int i = beg + tid; i < end; i += 256) {
            int d = dst[i], s = src[i];
            int r = d / rngB;
#pragma unroll
            for (int rr = 0; rr < NRANGE; ++rr) {
                unsigned long long m = __ballot(r == rr);
                if (m) {
                    int leader = __ffsll((long long)m) - 1;
                    unsigned b2r = 0;
                    if (lane == leader) b2r = atomicAdd(&lds[rr], (unsigned)__popcll(m));
                    b2r = (unsigned)__shfl((int)b2r, leader);
                    if (r == rr) {
                        unsigned before = (unsigned)__popcll(m & ((1ull << lane) - 1ull));
                        ebuf[sb[rr] + b2r + before] = make_uint2((unsigned)s, (unsigned)d);
                    }
                }
            }
        }
        __syncthreads();
    }
    for (int t = bid; t < NB; t += GRID) {        // blocksum
        int i = t * 256 + tid;
        unsigned v = (i < N) ? deg_d[i] : 0u;
#pragma unroll
        for (int off = 32; off; off >>= 1) v += __shfl_xor((int)v, off);
        __syncthreads();
        if ((tid & 63) == 0) lds[tid >> 6] = v;
        __syncthreads();
        if (tid == 0) partial[t] = lds[0] + lds[1] + lds[2] + lds[3];
        __syncthreads();
    }
    {                                             // gemm tiles
        _Float16* xs = (_Float16*)lds;
        for (int tile = bid; tile < ntiles; tile += GRID) {
            const int wv = tid >> 6;
            const int r0 = tile * 64;
            f16x8 bf[4][4];
#pragma unroll
            for (int kt = 0; kt < 4; ++kt)
#pragma unroll
                for (int nt = 0; nt < 4; ++nt)
                    bf[kt][nt] = *(const f16x8*)&wt[(nt * 16 + (lane & 15)) * 128 +
                                                    kt * 32 + (lane >> 4) * 8];
            __syncthreads();
#pragma unroll
            for (int it = 0; it < 8; ++it) {
                int e = it * 256 + tid;
                int r = e >> 5, cc = e & 31;
                int row = r0 + r;
                float4 v = (row < N) ? ((const float4*)x)[(size_t)row * 32 + cc]
                                     : make_float4(0.f, 0.f, 0.f, 0.f);
                __half2 lo2 = __floats2half2_rn(v.x, v.y);
                __half2 hi2 = __floats2half2_rn(v.z, v.w);
                uint2 pk;
                pk.x = *(unsigned*)&lo2;
                pk.y = *(unsigned*)&hi2;
                int byte = r * 256 + cc * 8;
                byte ^= (r & 7) << 4;
                *(uint2*)((char*)xs + byte) = pk;
            }
            __syncthreads();
            f32x4 acc[4] = {};
            const int rloc = wv * 16 + (lane & 15);
#pragma unroll
            for (int kt = 0; kt < 4; ++kt) {
                int byte = rloc * 256 + (kt * 32 + (lane >> 4) * 8) * 2;
                byte ^= (rloc & 7) << 4;
                f16x8 af = *(const f16x8*)((char*)xs + byte);
#pragma unroll
                for (int nt = 0; nt < 4; ++nt)
                    acc[nt] = __builtin_amdgcn_mfma_f32_16x16x32_f16(af, bf[kt][nt], acc[nt], 0, 0, 0);
            }
#pragma unroll
            for (int j = 0; j < 4; ++j) {
                int row = r0 + wv * 16 + (lane >> 4) * 4 + j;
                if (row < N) {
                    float ns = norm_s[row];
#pragma unroll
                    for (int nt = 0; nt < 4; ++nt)
                        h1h[(size_t)row * 64 + nt * 16 + (lane & 15)] =
                            __float2half(acc[nt][j] * ns);
                }
            }
            __syncthreads();
        }
    }
    grid.sync();

    // ================= PH3: scanpartial (block 0, PER=2) =================
    if (bid == 0) {
        unsigned p0 = (2 * tid < NB) ? partial[2 * tid] : 0u;
        unsigned p1 = (2 * tid + 1 < NB) ? partial[2 * tid + 1] : 0u;
        unsigned sum = p0 + p1;
        lds[tid] = sum;
        __syncthreads();
        for (int off = 1; off < 256; off <<= 1) {
            unsigned a = (tid >= off) ? lds[tid - off] : 0u;
            __syncthreads();
            lds[tid] += a;
            __syncthreads();
        }
        unsigned excl = lds[tid] - sum;
        if (2 * tid < NB) blockoff[2 * tid] = excl;
        if (2 * tid + 1 < NB) blockoff[2 * tid + 1] = excl + p0;
        if (tid == 255) offsets[N] = lds[255];    // = E
    }
    grid.sync();

    // ================= PH4: offsets =================
    for (int t = bid; t < NB; t += GRID) {
        int i = t * 256 + tid;
        unsigned v = (i < N) ? deg_d[i] : 0u;
        __syncthreads();
        lds[tid] = v;
        __syncthreads();
        for (int off = 1; off < 256; off <<= 1) {
            unsigned a = (tid >= off) ? lds[tid - off] : 0u;
            __syncthreads();
            lds[tid] += a;
            __syncthreads();
        }
        if (i < N) offsets[i] = blockoff[t] + lds[tid] - v;
        __syncthreads();
    }
    grid.sync();

    // ================= PH5: fill (512 tasks, XCD-aligned half-range) ======
    {
        const int hr = bid & 15;
        const int ch = bid >> 4;                  // 0..CHK-1
        const int r  = hr >> 1;
        const int lo = hr * hb;
        const int bins = min(hb, N - lo);
        const int hq = hr >> 2, sh = (hr & 3) << 3;
        const unsigned* relp = partial_d + (size_t)(hq * CHK + ch) * hb;
        for (int b = tid; b < bins; b += 256)
            lds[b] = offsets[lo + b] + ((relp[b] >> sh) & 0xffu);
        __syncthreads();
        const unsigned s0 = segBase[r * CB + ch * RB];
        const unsigned s1 = segBase[r * CB + ch * RB + RB];
        for (unsigned i = s0 + tid; i < s1; i += 256) {
            uint2 e = ebuf[i];
            int a = (int)e.y - lo;
            if ((unsigned)a < (unsigned)bins)
                csr[atomicAdd(&lds[a], 1u)] = e.x;
        }
    }
}

// One wave per node; uint2/lane gathers: 16 lanes/edge (4 ch each), 4 edges
// per instruction, up to 8 loads = 32 edges in flight.
__global__ __launch_bounds__(256) void k_agg_rdot(const unsigned* __restrict__ offsets,
                                                  const unsigned* __restrict__ csr,
                                                  const __half* __restrict__ h1h,
                                                  const float* __restrict__ norm_s,
                                                  const float* __restrict__ norm_d,
                                                  const float* __restrict__ b1,
                                                  const float* __restrict__ w2l,
                                                  float* __restrict__ s_node, int N) {
    const int lane = threadIdx.x & 63;
    const int slot = lane >> 4;
    const int p = lane & 15;
    const int v = (blockIdx.x * 256 + threadIdx.x) >> 6;
    if (v >= N) return;
    const unsigned beg = offsets[v], end = offsets[v + 1];

    float a0 = 0.f, a1 = 0.f, a2 = 0.f, a3 = 0.f;
#define GATHER(sreg) { \
        uint2 u = *(const uint2*)&h1h[(size_t)(sreg) * 64 + 4 * p]; \
        float2 f0 = __half22float2(*(__half2*)&u.x); \
        float2 f1 = __half22float2(*(__half2*)&u.y); \
        a0 += f0.x; a1 += f0.y; a2 += f1.x; a3 += f1.y; }

    for (unsigned base = beg; base < end; base += WAVE) {
        const int n = (int)min((unsigned)WAVE, end - base);
        int sv = (lane < n) ? (int)csr[base + lane] : 0;
        int i = 0;
        for (; i + 32 <= n; i += 32) {
            int s0 = __shfl(sv, i + 0 + slot);
            int s1 = __shfl(sv, i + 4 + slot);
            int s2 = __shfl(sv, i + 8 + slot);
            int s3 = __shfl(sv, i + 12 + slot);
            int s4 = __shfl(sv, i + 16 + slot);
            int s5 = __shfl(sv, i + 20 + slot);
            int s6 = __shfl(sv, i + 24 + slot);
            int s7 = __shfl(sv, i + 28 + slot);
            GATHER(s0); GATHER(s1); GATHER(s2); GATHER(s3);
            GATHER(s4); GATHER(s5); GATHER(s6); GATHER(s7);
        }
        for (; i + 16 <= n; i += 16) {
            int s0 = __shfl(sv, i + 0 + slot);
            int s1 = __shfl(sv, i + 4 + slot);
            int s2 = __shfl(sv, i + 8 + slot);
            int s3 = __shfl(sv, i + 12 + slot);
            GATHER(s0); GATHER(s1); GATHER(s2); GATHER(s3);
        }
        for (; i < n; i += 4) {
            int e = i + slot;
            int s = __shfl(sv, min(e, n - 1));
            if (e < n) GATHER(s);
        }
    }
#undef GATHER
    a0 += __shfl_xor(a0, 16); a0 += __shfl_xor(a0, 32);
    a1 += __shfl_xor(a1, 16); a1 += __shfl_xor(a1, 32);
    a2 += __shfl_xor(a2, 16); a2 += __shfl_xor(a2, 32);
    a3 += __shfl_xor(a3, 16); a3 += __shfl_xor(a3, 32);

    float nd = norm_d[v];
    float4 bq = *(const float4*)&b1[4 * p];
    float4 wq = *(const float4*)&w2l[4 * p];
    float t = fmaxf(fmaf(a0, nd, bq.x), 0.f) * wq.x
            + fmaxf(fmaf(a1, nd, bq.y), 0.f) * wq.y
            + fmaxf(fmaf(a2, nd, bq.z), 0.f) * wq.z
            + fmaxf(fmaf(a3, nd, bq.w), 0.f) * wq.w;
#pragma unroll
    for (int off = 8; off; off >>= 1) t += __shfl_xor(t, off);
    if (lane == 0) s_node[v] = t * norm_s[v];
}

// out[v] = nd[v] * sum_{in-edges} s_node[src] + c0
__global__ __launch_bounds__(256) void k_out(const unsigned* __restrict__ offsets,
                                             const unsigned* __restrict__ csr,
                                             const float* __restrict__ s_node,
                                             const float* __restrict__ norm_d,
                                             const float* __restrict__ c0,
                                             float* __restrict__ out, int N) {
    int v = blockIdx.x * 256 + threadIdx.x;
    if (v >= N) return;
    unsigned beg = offsets[v], end = offsets[v + 1];
    float sum = 0.f;
    unsigned j = beg;
    for (; j + 4 <= end; j += 4) {
        float a = s_node[csr[j + 0]], b = s_node[csr[j + 1]];
        float c = s_node[csr[j + 2]], d = s_node[csr[j + 3]];
        sum += (a + b) + (c + d);
    }
    for (; j < end; ++j) sum += s_node[csr[j]];
    out[v] = fmaf(sum, norm_d[v], *c0);
}

extern "C" void kernel_launch(void* const* d_in, const int* in_sizes, int n_in,
                              void* d_out, int out_size, void* d_ws, size_t ws_size,
                              hipStream_t stream) {
    const float* x  = (const float*)d_in[0];
    const int*   ei = (const int*)d_in[1];
    const float* W1 = (const float*)d_in[2];
    const float* b1 = (const float*)d_in[3];
    const float* W2 = (const float*)d_in[4];
    const float* b2 = (const float*)d_in[5];
    const float* Wl = (const float*)d_in[6];
    const float* bl = (const float*)d_in[7];

    int N = in_sizes[0] / 128;
    int E = in_sizes[1] / 2;
    const int* src = ei;
    const int* dst = ei + E;
    int NB = (N + 255) / 256;                     // 391 (must be <= 512)
    int hb = (N + 15) / 16;                       // 6250 bins per half-range
    int rngB = 2 * hb;                            // 12500 nodes per bucket range
    int chunkEb = (E + CB - 1) / CB;              // bucket chunk (~1563)
    int chunkE = chunkEb * RB;                    // hist chunk (%4 == 0)
    int ntiles = (N + 63) / 64;

    char* w = (char*)d_ws;
    auto alloc = [&](size_t bytes) -> void* {
        void* r = (void*)w;
        w += (bytes + 255) & ~(size_t)255;
        return r;
    };
    float*    norm_s    = (float*)alloc((size_t)N * 4);
    float*    norm_d    = (float*)alloc((size_t)N * 4);
    unsigned* deg_d     = (unsigned*)alloc((size_t)N * 4);
    unsigned* offsets   = (unsigned*)alloc((size_t)(N + 1) * 4);
    unsigned* partial   = (unsigned*)alloc((size_t)NB * 4);
    unsigned* blockoff  = (unsigned*)alloc((size_t)NB * 4);
    __half*   h1h       = (__half*)alloc((size_t)N * 64 * 2);
    unsigned* csr       = (unsigned*)alloc((size_t)E * 4);
    float*    s_node    = (float*)alloc((size_t)N * 4);
    float*    w2l       = (float*)alloc(64 * 4);
    float*    c0        = (float*)alloc(4);
    _Float16* wt        = (_Float16*)alloc(64 * 128 * 2);
    uint2*    ebuf      = (uint2*)alloc((size_t)E * 8);
    unsigned* cnt       = (unsigned*)alloc((size_t)(NRANGE * CB + 1) * 4);
    unsigned* segBase   = (unsigned*)alloc((size_t)(NRANGE * CB + 1) * 4);
    unsigned* partial_s = (unsigned*)alloc((size_t)4 * CHK * hb * 4);
    unsigned* partial_d = (unsigned*)alloc((size_t)4 * CHK * hb * 4);

    float* out = (float*)d_out;
    size_t ldsB = (size_t)hb * 4;
    if (ldsB < 16384) ldsB = 16384;               // gemm tile needs 16KB
    ldsB = (ldsB + 255) & ~(size_t)255;

    void* args[] = {
        (void*)&src, (void*)&dst, (void*)&x, (void*)&W1, (void*)&W2,
        (void*)&b2, (void*)&Wl, (void*)&bl,
        (void*)&cnt, (void*)&segBase, (void*)&ebuf,
        (void*)&partial_s, (void*)&partial_d,
        (void*)&norm_s, (void*)&norm_d, (void*)&deg_d,
        (void*)&partial, (void*)&blockoff, (void*)&offsets,
        (void*)&csr, (void*)&wt, (void*)&w2l, (void*)&c0, (void*)&h1h,
        (void*)&E, (void*)&N, (void*)&rngB, (void*)&hb,
        (void*)&chunkEb, (void*)&chunkE, (void*)&NB, (void*)&ntiles
    };
    hipLaunchCooperativeKernel((const void*)k_build, dim3(GRID), dim3(256),
                               args, (unsigned)ldsB, stream);

    k_agg_rdot<<<(N + 3) / 4, 256, 0, stream>>>(offsets, csr, h1h, norm_s,
                                                norm_d, b1, w2l, s_node, N);
    k_out<<<NB, 256, 0, stream>>>(offsets, csr, s_node, norm_d, c0, out, N);
}

// Round 15
// 188.508 us; speedup vs baseline: 2.4479x; 2.4479x over previous
//
#include <hip/hip_runtime.h>
#include <hip/hip_fp16.h>

// GCN on MI355X — bucket-sort CSR build (atomic window offsets) + fp16 gather + MFMA.
//
// Algebra: layer2 collapses through the linear head:
//   out = segsum((relu(c1) . (W2@Wl) * ns)[src], dst)*nd + (b2@Wl + bl)
// so only a per-node SCALAR feeds the second aggregation.
//
// R14 (after R13's coop-kernel failure: grid.sync + 2-block/CU cap = 399us):
// revert to R9/R10 pipeline, remove stages WITHOUT structure damage:
//  (1) offsets need not be node-ordered, only disjoint + confined to the
//      range's XCD window: k_reduce_norm assigns offsets[n] via wave-
//      aggregated atomicAdd on rangeCur[r] (kills blocksum/scanpartial/
//      offsets = 3 dispatches). agg/out use end = beg + deg.
//  (2) prep folds into k_cnt (extra block); rangeCur seed folds into
//      k_scancnt2; no memsets. 13 -> 9 dispatches.

#define WAVE 64
#define NRANGE 8
#define NQUAD 2
#define CB 1024
#define CHK 32
#define RB (CB / CHK)      // 32

typedef _Float16 f16x8 __attribute__((ext_vector_type(8)));
typedef float f32x4 __attribute__((ext_vector_type(4)));

// ---- per-(range, bucket-chunk) counts; block CB does weight prep ----
__global__ __launch_bounds__(256) void k_cnt(const int* __restrict__ dst,
                                             unsigned* __restrict__ cnt,
                                             int E, int B, int chunkEb,
                                             const float* __restrict__ W1,
                                             const float* __restrict__ W2,
                                             const float* __restrict__ b2,
                                             const float* __restrict__ Wl,
                                             const float* __restrict__ bl,
                                             _Float16* __restrict__ wt,
                                             float* __restrict__ w2l,
                                             float* __restrict__ c0) {
    if (blockIdx.x == CB) {                       // prep: wt, w2l, c0
        int t = threadIdx.x;
        for (int i = 0; i < 32; ++i) {
            int e = i * 256 + t;
            int k = e >> 6, n = e & 63;
            wt[n * 128 + k] = (_Float16)W1[e];
        }
        if (t < 64) {
            float acc = 0.f;
#pragma unroll
            for (int j = 0; j < 32; ++j) acc += W2[t * 32 + j] * Wl[j];
            w2l[t] = acc;
        }
        if (t == 0) {
            float s = 0.f;
#pragma unroll
            for (int j = 0; j < 32; ++j) s += b2[j] * Wl[j];
            *c0 = s + bl[0];
        }
        return;
    }
    __shared__ unsigned lc[NRANGE];
    if (threadIdx.x < NRANGE) lc[threadIdx.x] = 0u;
    __syncthreads();
    const int c = blockIdx.x;
    const int beg = c * chunkEb, end = min(beg + chunkEb, E);
    unsigned pc[NRANGE] = {};
    for (int i = beg + (int)threadIdx.x; i < end; i += 256) {
        int r = dst[i] / B;
#pragma unroll
        for (int rr = 0; rr < NRANGE; ++rr) pc[rr] += (r == rr);
    }
#pragma unroll
    for (int rr = 0; rr < NRANGE; ++rr) {
        unsigned v = pc[rr];
#pragma unroll
        for (int off = 32; off; off >>= 1) v += __shfl_xor((int)v, off);
        if ((threadIdx.x & 63) == 0 && v) atomicAdd(&lc[rr], v);
    }
    __syncthreads();
    if (threadIdx.x < NRANGE) cnt[threadIdx.x * CB + c] = lc[threadIdx.x];
}

// ---- exclusive scan of cnt -> segBase; seed rangeCur[r] = r*SLOT ----
__global__ __launch_bounds__(256) void k_scancnt2(const unsigned* __restrict__ cnt,
                                                  unsigned* __restrict__ segBase,
                                                  unsigned* __restrict__ rangeCur,
                                                  int SLOT) {
    __shared__ unsigned s[256];
    const int t = threadIdx.x;
    const int PER = (NRANGE * CB) / 256;          // 32
    unsigned loc[PER];
    unsigned sum = 0;
#pragma unroll
    for (int j = 0; j < PER; ++j) { loc[j] = sum; sum += cnt[t * PER + j]; }
    s[t] = sum;
    __syncthreads();
    for (int off = 1; off < 256; off <<= 1) {
        unsigned a = (t >= off) ? s[t - off] : 0u;
        __syncthreads();
        s[t] += a;
        __syncthreads();
    }
    unsigned base = s[t] - sum;
#pragma unroll
    for (int j = 0; j < PER; ++j) segBase[t * PER + j] = base + loc[j];
    if (t == 255) segBase[NRANGE * CB] = s[255];
    if (t < NRANGE) rangeCur[t] = (unsigned)(t * SLOT);
}

// ---- byte-packed histogram: block (q,c) covers ranges 4q..4q+3; y: src/dst ----
__global__ __launch_bounds__(256) void k_hist(const int* __restrict__ srcArr,
                                              const int* __restrict__ dstArr,
                                              unsigned* __restrict__ partial_s,
                                              unsigned* __restrict__ partial_d,
                                              int E, int B, int chunkE) {
    extern __shared__ unsigned hist[];
    const int q = blockIdx.x & (NQUAD - 1);
    const int c = blockIdx.x >> 1;
    const int lo = q * 4 * B;
    const int* nodes = blockIdx.y ? dstArr : srcArr;
    unsigned* partial = blockIdx.y ? partial_d : partial_s;

    for (int b = threadIdx.x; b < B; b += 256) hist[b] = 0u;
    __syncthreads();

    const int beg = c * chunkE, end = min(beg + chunkE, E);
    const int n4 = (end - beg) >> 2;              // beg 4-aligned
    const int4* p = (const int4*)(nodes + beg);
    for (int j = threadIdx.x; j < n4; j += 256) {
        int4 v = p[j];
#pragma unroll
        for (int k = 0; k < 4; ++k) {
            int a = (&v.x)[k] - lo;
            if ((unsigned)a < (unsigned)(4 * B)) {
                int h2 = (a >= 2 * B);
                int r2 = a - (h2 ? 2 * B : 0);
                int h1 = (r2 >= B);
                int bin = r2 - (h1 ? B : 0);
                atomicAdd(&hist[bin], 1u << (((h2 << 1) | h1) << 3));
            }
        }
    }
    for (int j = beg + (n4 << 2) + threadIdx.x; j < end; j += 256) {
        int a = nodes[j] - lo;
        if ((unsigned)a < (unsigned)(4 * B)) {
            int h2 = (a >= 2 * B);
            int r2 = a - (h2 ? 2 * B : 0);
            int h1 = (r2 >= B);
            int bin = r2 - (h1 ? B : 0);
            atomicAdd(&hist[bin], 1u << (((h2 << 1) | h1) << 3));
        }
    }
    __syncthreads();
    unsigned* outp = partial + (size_t)(q * CHK + c) * B;
    for (int b = threadIdx.x; b < B; b += 256) outp[b] = hist[b];
}

// ---- bucketize: ballot-ranked append into per-(range,chunk) segments ----
__global__ __launch_bounds__(256) void k_bucket(const int* __restrict__ src,
                                                const int* __restrict__ dst,
                                                const unsigned* __restrict__ segBase,
                                                uint2* __restrict__ ebuf,
                                                int E, int B, int chunkEb) {
    __shared__ unsigned lcnt[NRANGE];
    const int c = blockIdx.x;
    const int lane = threadIdx.x & 63;
    if (threadIdx.x < NRANGE) lcnt[threadIdx.x] = 0u;
    __syncthreads();

    unsigned sb[NRANGE];
#pragma unroll
    for (int r = 0; r < NRANGE; ++r) sb[r] = segBase[r * CB + c];

    const int beg = c * chunkEb, end = min(beg + chunkEb, E);
    for (int i = beg + (int)threadIdx.x; i < end; i += 256) {
        int d = dst[i];
        int s = src[i];
        int r = d / B;
#pragma unroll
        for (int rr = 0; rr < NRANGE; ++rr) {
            unsigned long long m = __ballot(r == rr);
            if (m) {
                int leader = __ffsll((long long)m) - 1;
                unsigned base = 0;
                if (lane == leader) base = atomicAdd(&lcnt[rr], (unsigned)__popcll(m));
                base = (unsigned)__shfl((int)base, leader);
                if (r == rr) {
                    unsigned before = (unsigned)__popcll(m & ((1ull << lane) - 1ull));
                    ebuf[sb[rr] + base + before] = make_uint2((unsigned)s, (unsigned)d);
                }
            }
        }
    }
}

// ---- reduce_norm + ATOMIC WINDOW OFFSETS (replaces 3-stage scan chain) ----
// thread t -> (q = t/Bpad, b = t%Bpad); Bpad%64==0 so q is wave-uniform.
// For each byte-lane j (range r = q*4+j): wave-scan deg, ONE atomicAdd
// on rangeCur[r] per wave, distribute bases via shfl.
__global__ __launch_bounds__(256) void k_reduce_norm(const unsigned* __restrict__ partial_s,
                                                     unsigned* __restrict__ partial_d,
                                                     float* __restrict__ norm_s,
                                                     float* __restrict__ norm_d,
                                                     unsigned* __restrict__ deg_d,
                                                     unsigned* __restrict__ offsets,
                                                     unsigned* __restrict__ rangeCur,
                                                     int N, int B, int Bpad) {
    int t = blockIdx.x * 256 + threadIdx.x;
    int lane = threadIdx.x & 63;
    int q = t / Bpad, b = t - q * Bpad;
    bool valid = (q < NQUAD) && (b < B);
    unsigned ds = 0, run = 0;
    if (valid) {
        size_t base = (size_t)(q * CHK) * B + b;
        for (int c = 0; c < CHK; ++c) ds += partial_s[base + (size_t)c * B];
        unsigned acc = 0;
        for (int c = 0; c < CHK; ++c) {
            size_t ix = base + (size_t)c * B;
            unsigned v = partial_d[ix];
            partial_d[ix] = acc;                  // packed exclusive prefix
            acc += v;
        }
        run = acc;
    }
#pragma unroll
    for (int j = 0; j < 4; ++j) {
        unsigned d1 = valid ? ((run >> (8 * j)) & 0xffu) : 0u;
        unsigned p = d1;                          // inclusive wave scan
#pragma unroll
        for (int off = 1; off < 64; off <<= 1) {
            unsigned o = (unsigned)__shfl_up((int)p, off);
            if (lane >= off) p += o;
        }
        unsigned tot = (unsigned)__shfl((int)p, 63);
        int r = q * 4 + j;                        // wave-uniform
        unsigned wbase = 0;
        if (lane == 63 && tot) wbase = atomicAdd(&rangeCur[r], tot);
        wbase = (unsigned)__shfl((int)wbase, 63);
        if (valid) {
            int n = q * 4 * B + j * B + b;
            if (n < N) {
                unsigned d0 = (ds >> (8 * j)) & 0xffu;
                deg_d[n] = d1;
                norm_s[n] = d0 ? rsqrtf((float)d0) : 0.0f;
                norm_d[n] = d1 ? rsqrtf((float)d1) : 0.0f;
                offsets[n] = wbase + (p - d1);
            }
        }
    }
}

// ---- fill: block (r,ch) reads its contiguous ebuf span; LDS absolute cursors;
//      r = blockIdx&7 -> XCD-aligned csr window ----
__global__ __launch_bounds__(256) void k_fill2(const uint2* __restrict__ ebuf,
                                               const unsigned* __restrict__ segBase,
                                               const unsigned* __restrict__ offsets,
                                               const unsigned* __restrict__ rel,
                                               unsigned* __restrict__ csr,
                                               int N, int B) {
    extern __shared__ unsigned curs[];
    const int r = blockIdx.x & (NRANGE - 1);
    const int ch = blockIdx.x >> 3;
    const int lo = r * B;
    const int bins = min(B, N - lo);
    const int sh = (r & 3) << 3;
    const unsigned* relp = rel + (size_t)((r >> 2) * CHK + ch) * B;
    for (int b = threadIdx.x; b < bins; b += 256)
        curs[b] = offsets[lo + b] + ((relp[b] >> sh) & 0xffu);
    __syncthreads();

    const unsigned s0 = segBase[r * CB + ch * RB];
    const unsigned s1 = segBase[r * CB + ch * RB + RB];
    for (unsigned i = s0 + threadIdx.x; i < s1; i += 256) {
        uint2 e = ebuf[i];
        int a = (int)e.y - lo;
        if ((unsigned)a < (unsigned)bins)
            csr[atomicAdd(&curs[a], 1u)] = e.x;
    }
}

// h1h = fp16( (x * ns[:,None]) @ W1 )  via MFMA 16x16x32_f16.
__global__ __launch_bounds__(256) void k_gemm1(const float* __restrict__ x,
                                               const _Float16* __restrict__ wt,
                                               const float* __restrict__ norm_s,
                                               __half* __restrict__ h1h, int N) {
    __shared__ __align__(16) _Float16 xs[64 * 128];
    const int tid = threadIdx.x, lane = tid & 63, wv = tid >> 6;
    const int r0 = blockIdx.x * 64;

    f16x8 bf[4][4];
#pragma unroll
    for (int kt = 0; kt < 4; ++kt)
#pragma unroll
        for (int nt = 0; nt < 4; ++nt)
            bf[kt][nt] = *(const f16x8*)&wt[(nt * 16 + (lane & 15)) * 128 +
                                            kt * 32 + (lane >> 4) * 8];

#pragma unroll
    for (int it = 0; it < 8; ++it) {
        int e = it * 256 + tid;
        int r = e >> 5, c = e & 31;
        int row = r0 + r;
        float4 v = (row < N) ? ((const float4*)x)[(size_t)row * 32 + c]
                             : make_float4(0.f, 0.f, 0.f, 0.f);
        __half2 lo2 = __floats2half2_rn(v.x, v.y);
        __half2 hi2 = __floats2half2_rn(v.z, v.w);
        uint2 pk;
        pk.x = *(unsigned*)&lo2;
        pk.y = *(unsigned*)&hi2;
        int byte = r * 256 + c * 8;
        byte ^= (r & 7) << 4;
        *(uint2*)((char*)xs + byte) = pk;
    }
    __syncthreads();

    f32x4 acc[4] = {};
    const int rloc = wv * 16 + (lane & 15);
#pragma unroll
    for (int kt = 0; kt < 4; ++kt) {
        int byte = rloc * 256 + (kt * 32 + (lane >> 4) * 8) * 2;
        byte ^= (rloc & 7) << 4;
        f16x8 af = *(const f16x8*)((char*)xs + byte);
#pragma unroll
        for (int nt = 0; nt < 4; ++nt)
            acc[nt] = __builtin_amdgcn_mfma_f32_16x16x32_f16(af, bf[kt][nt], acc[nt], 0, 0, 0);
    }

#pragma unroll
    for (int j = 0; j < 4; ++j) {
        int row = r0 + wv * 16 + (lane >> 4) * 4 + j;
        if (row < N) {
            float ns = norm_s[row];
#pragma unroll
            for (int nt = 0; nt < 4; ++nt)
                h1h[(size_t)row * 64 + nt * 16 + (lane & 15)] =
                    __float2half(acc[nt][j] * ns);
        }
    }
}

// One wave per node; uint2/lane gathers: 16 lanes/edge (4 ch each), 4 edges
// per instruction, up to 8 loads = 32 edges in flight.
__global__ __launch_bounds__(256) void k_agg_rdot(const unsigned* __restrict__ offsets,
                                                  const unsigned* __restrict__ deg_d,
                                                  const unsigned* __restrict__ csr,
                                                  const __half* __restrict__ h1h,
                                                  const float* __restrict__ norm_s,
                                                  const float* __restrict__ norm_d,
                                                  const float* __restrict__ b1,
                                                  const float* __restrict__ w2l,
                                                  float* __restrict__ s_node, int N) {
    const int lane = threadIdx.x & 63;
    const int slot = lane >> 4;
    const int p = lane & 15;
    const int v = (blockIdx.x * 256 + threadIdx.x) >> 6;
    if (v >= N) return;
    const unsigned beg = offsets[v];
    const unsigned end = beg + deg_d[v];

    float a0 = 0.f, a1 = 0.f, a2 = 0.f, a3 = 0.f;
#define GATHER(sreg) { \
        uint2 u = *(const uint2*)&h1h[(size_t)(sreg) * 64 + 4 * p]; \
        float2 f0 = __half22float2(*(__half2*)&u.x); \
        float2 f1 = __half22float2(*(__half2*)&u.y); \
        a0 += f0.x; a1 += f0.y; a2 += f1.x; a3 += f1.y; }

    for (unsigned base = beg; base < end; base += WAVE) {
        const int n = (int)min((unsigned)WAVE, end - base);
        int sv = (lane < n) ? (int)csr[base + lane] : 0;
        int i = 0;
        for (; i + 32 <= n; i += 32) {
            int s0 = __shfl(sv, i + 0 + slot);
            int s1 = __shfl(sv, i + 4 + slot);
            int s2 = __shfl(sv, i + 8 + slot);
            int s3 = __shfl(sv, i + 12 + slot);
            int s4 = __shfl(sv, i + 16 + slot);
            int s5 = __shfl(sv, i + 20 + slot);
            int s6 = __shfl(sv, i + 24 + slot);
            int s7 = __shfl(sv, i + 28 + slot);
            GATHER(s0); GATHER(s1); GATHER(s2); GATHER(s3);
            GATHER(s4); GATHER(s5); GATHER(s6); GATHER(s7);
        }
        for (; i + 16 <= n; i += 16) {
            int s0 = __shfl(sv, i + 0 + slot);
            int s1 = __shfl(sv, i + 4 + slot);
            int s2 = __shfl(sv, i + 8 + slot);
            int s3 = __shfl(sv, i + 12 + slot);
            GATHER(s0); GATHER(s1); GATHER(s2); GATHER(s3);
        }
        for (; i < n; i += 4) {
            int e = i + slot;
            int s = __shfl(sv, min(e, n - 1));
            if (e < n) GATHER(s);
        }
    }
#undef GATHER
    a0 += __shfl_xor(a0, 16); a0 += __shfl_xor(a0, 32);
    a1 += __shfl_xor(a1, 16); a1 += __shfl_xor(a1, 32);
    a2 += __shfl_xor(a2, 16); a2 += __shfl_xor(a2, 32);
    a3 += __shfl_xor(a3, 16); a3 += __shfl_xor(a3, 32);

    float nd = norm_d[v];
    float4 bq = *(const float4*)&b1[4 * p];
    float4 wq = *(const float4*)&w2l[4 * p];
    float t = fmaxf(fmaf(a0, nd, bq.x), 0.f) * wq.x
            + fmaxf(fmaf(a1, nd, bq.y), 0.f) * wq.y
            + fmaxf(fmaf(a2, nd, bq.z), 0.f) * wq.z
            + fmaxf(fmaf(a3, nd, bq.w), 0.f) * wq.w;
#pragma unroll
    for (int off = 8; off; off >>= 1) t += __shfl_xor(t, off);
    if (lane == 0) s_node[v] = t * norm_s[v];
}

// out[v] = nd[v] * sum_{in-edges} s_node[src] + c0
__global__ __launch_bounds__(256) void k_out(const unsigned* __restrict__ offsets,
                                             const unsigned* __restrict__ deg_d,
                                             const unsigned* __restrict__ csr,
                                             const float* __restrict__ s_node,
                                             const float* __restrict__ norm_d,
                                             const float* __restrict__ c0,
                                             float* __restrict__ out, int N) {
    int v = blockIdx.x * 256 + threadIdx.x;
    if (v >= N) return;
    unsigned beg = offsets[v], end = beg + deg_d[v];
    float sum = 0.f;
    unsigned j = beg;
    for (; j + 4 <= end; j += 4) {
        float a = s_node[csr[j + 0]], b = s_node[csr[j + 1]];
        float c = s_node[csr[j + 2]], d = s_node[csr[j + 3]];
        sum += (a + b) + (c + d);
    }
    for (; j < end; ++j) sum += s_node[csr[j]];
    out[v] = fmaf(sum, norm_d[v], *c0);
}

extern "C" void kernel_launch(void* const* d_in, const int* in_sizes, int n_in,
                              void* d_out, int out_size, void* d_ws, size_t ws_size,
                              hipStream_t stream) {
    const float* x  = (const float*)d_in[0];
    const int*   ei = (const int*)d_in[1];
    const float* W1 = (const float*)d_in[2];
    const float* b1 = (const float*)d_in[3];
    const float* W2 = (const float*)d_in[4];
    const float* b2 = (const float*)d_in[5];
    const float* Wl = (const float*)d_in[6];
    const float* bl = (const float*)d_in[7];

    const int N = in_sizes[0] / 128;
    const int E = in_sizes[1] / 2;
    const int* src = ei;
    const int* dst = ei + E;
    const int NB = (N + 255) / 256;
    const int B = (N + NRANGE - 1) / NRANGE;        // 12500
    const int Bpad = ((B + 63) / 64) * 64;          // wave-uniform q mapping
    const int SLOT = E / NRANGE + 16384;            // per-range csr window
    const int chunkEb = (E + CB - 1) / CB;
    const int chunkE = chunkEb * RB;                // hist chunk, %4==0

    char* w = (char*)d_ws;
    auto alloc = [&](size_t bytes) -> void* {
        void* r = (void*)w;
        w += (bytes + 255) & ~(size_t)255;
        return r;
    };
    float*    norm_s    = (float*)alloc((size_t)N * 4);
    float*    norm_d    = (float*)alloc((size_t)N * 4);
    unsigned* deg_d     = (unsigned*)alloc((size_t)N * 4);
    unsigned* offsets   = (unsigned*)alloc((size_t)N * 4);
    __half*   h1h       = (__half*)alloc((size_t)N * 64 * 2);
    unsigned* csr       = (unsigned*)alloc((size_t)NRANGE * SLOT * 4);
    float*    s_node    = (float*)alloc((size_t)N * 4);
    float*    w2l       = (float*)alloc(64 * 4);
    float*    c0        = (float*)alloc(4);
    _Float16* wt        = (_Float16*)alloc(64 * 128 * 2);
    uint2*    ebuf      = (uint2*)alloc((size_t)E * 8);
    unsigned* cnt       = (unsigned*)alloc((size_t)(NRANGE * CB + 1) * 4);
    unsigned* segBase   = (unsigned*)alloc((size_t)(NRANGE * CB + 1) * 4);
    unsigned* rangeCur  = (unsigned*)alloc(NRANGE * 4);
    unsigned* partial_s = (unsigned*)alloc((size_t)NQUAD * CHK * B * 4);
    unsigned* partial_d = (unsigned*)alloc((size_t)NQUAD * CHK * B * 4);

    float* out = (float*)d_out;
    const size_t ldsB = (size_t)B * 4;

    k_cnt<<<CB + 1, 256, 0, stream>>>(dst, cnt, E, B, chunkEb,
                                      W1, W2, b2, Wl, bl, wt, w2l, c0);
    k_scancnt2<<<1, 256, 0, stream>>>(cnt, segBase, rangeCur, SLOT);
    k_hist<<<dim3(NQUAD * CHK, 2), 256, ldsB, stream>>>(src, dst, partial_s,
                                                        partial_d, E, B, chunkE);
    k_bucket<<<CB, 256, 0, stream>>>(src, dst, segBase, ebuf, E, B, chunkEb);

    k_reduce_norm<<<(NQUAD * Bpad + 255) / 256, 256, 0, stream>>>(
        partial_s, partial_d, norm_s, norm_d, deg_d, offsets, rangeCur,
        N, B, Bpad);

    k_gemm1<<<(N + 63) / 64, 256, 0, stream>>>(x, wt, norm_s, h1h, N);

    k_fill2<<<NRANGE * CHK, 256, ldsB, stream>>>(ebuf, segBase, offsets,
                                                 partial_d, csr, N, B);

    k_agg_rdot<<<(N + 3) / 4, 256, 0, stream>>>(offsets, deg_d, csr, h1h,
                                                norm_s, norm_d, b1, w2l,
                                                s_node, N);
    k_out<<<NB, 256, 0, stream>>>(offsets, deg_d, csr, s_node, norm_d, c0, out, N);
}

// Round 16
// 184.452 us; speedup vs baseline: 2.5017x; 1.0220x over previous
//
#include <hip/hip_runtime.h>
#include <hip/hip_fp16.h>

// GCN on MI355X — bucket-sort CSR build (atomic window offsets) + fp16 gather + MFMA.
//
// Algebra: layer2 collapses through the linear head:
//   out = segsum((relu(c1) . (W2@Wl) * ns)[src], dst)*nd + (b2@Wl + bl)
// so only a per-node SCALAR feeds the second aggregation.
//
// R15 (tail = real work in under-parallelized kernels, gaps only ~1.5us):
//  (1) k_out: 4 lanes/node (was 1 thread/node @20% thread capacity, serial loop).
//  (2) k_reduce_norm: s-role / d-role thread split (2x parallelism; the
//      partial_s sum and partial_d scan are independent).
//  (3) ebuf packed to u32 = (bin<<17)|src — halves bucket/fill traffic.

#define WAVE 64
#define NRANGE 8
#define NQUAD 2
#define CB 1024
#define CHK 32
#define RB (CB / CHK)      // 32

typedef _Float16 f16x8 __attribute__((ext_vector_type(8)));
typedef float f32x4 __attribute__((ext_vector_type(4)));

// ---- per-(range, bucket-chunk) counts; block CB does weight prep ----
__global__ __launch_bounds__(256) void k_cnt(const int* __restrict__ dst,
                                             unsigned* __restrict__ cnt,
                                             int E, int B, int chunkEb,
                                             const float* __restrict__ W1,
                                             const float* __restrict__ W2,
                                             const float* __restrict__ b2,
                                             const float* __restrict__ Wl,
                                             const float* __restrict__ bl,
                                             _Float16* __restrict__ wt,
                                             float* __restrict__ w2l,
                                             float* __restrict__ c0) {
    if (blockIdx.x == CB) {                       // prep: wt, w2l, c0
        int t = threadIdx.x;
        for (int i = 0; i < 32; ++i) {
            int e = i * 256 + t;
            int k = e >> 6, n = e & 63;
            wt[n * 128 + k] = (_Float16)W1[e];
        }
        if (t < 64) {
            float acc = 0.f;
#pragma unroll
            for (int j = 0; j < 32; ++j) acc += W2[t * 32 + j] * Wl[j];
            w2l[t] = acc;
        }
        if (t == 0) {
            float s = 0.f;
#pragma unroll
            for (int j = 0; j < 32; ++j) s += b2[j] * Wl[j];
            *c0 = s + bl[0];
        }
        return;
    }
    __shared__ unsigned lc[NRANGE];
    if (threadIdx.x < NRANGE) lc[threadIdx.x] = 0u;
    __syncthreads();
    const int c = blockIdx.x;
    const int beg = c * chunkEb, end = min(beg + chunkEb, E);
    unsigned pc[NRANGE] = {};
    for (int i = beg + (int)threadIdx.x; i < end; i += 256) {
        int r = dst[i] / B;
#pragma unroll
        for (int rr = 0; rr < NRANGE; ++rr) pc[rr] += (r == rr);
    }
#pragma unroll
    for (int rr = 0; rr < NRANGE; ++rr) {
        unsigned v = pc[rr];
#pragma unroll
        for (int off = 32; off; off >>= 1) v += __shfl_xor((int)v, off);
        if ((threadIdx.x & 63) == 0 && v) atomicAdd(&lc[rr], v);
    }
    __syncthreads();
    if (threadIdx.x < NRANGE) cnt[threadIdx.x * CB + c] = lc[threadIdx.x];
}

// ---- exclusive scan of cnt -> segBase; seed rangeCur[r] = r*SLOT ----
__global__ __launch_bounds__(256) void k_scancnt2(const unsigned* __restrict__ cnt,
                                                  unsigned* __restrict__ segBase,
                                                  unsigned* __restrict__ rangeCur,
                                                  int SLOT) {
    __shared__ unsigned s[256];
    const int t = threadIdx.x;
    const int PER = (NRANGE * CB) / 256;          // 32
    unsigned loc[PER];
    unsigned sum = 0;
#pragma unroll
    for (int j = 0; j < PER; ++j) { loc[j] = sum; sum += cnt[t * PER + j]; }
    s[t] = sum;
    __syncthreads();
    for (int off = 1; off < 256; off <<= 1) {
        unsigned a = (t >= off) ? s[t - off] : 0u;
        __syncthreads();
        s[t] += a;
        __syncthreads();
    }
    unsigned base = s[t] - sum;
#pragma unroll
    for (int j = 0; j < PER; ++j) segBase[t * PER + j] = base + loc[j];
    if (t == 255) segBase[NRANGE * CB] = s[255];
    if (t < NRANGE) rangeCur[t] = (unsigned)(t * SLOT);
}

// ---- byte-packed histogram: block (q,c) covers ranges 4q..4q+3; y: src/dst ----
__global__ __launch_bounds__(256) void k_hist(const int* __restrict__ srcArr,
                                              const int* __restrict__ dstArr,
                                              unsigned* __restrict__ partial_s,
                                              unsigned* __restrict__ partial_d,
                                              int E, int B, int chunkE) {
    extern __shared__ unsigned hist[];
    const int q = blockIdx.x & (NQUAD - 1);
    const int c = blockIdx.x >> 1;
    const int lo = q * 4 * B;
    const int* nodes = blockIdx.y ? dstArr : srcArr;
    unsigned* partial = blockIdx.y ? partial_d : partial_s;

    for (int b = threadIdx.x; b < B; b += 256) hist[b] = 0u;
    __syncthreads();

    const int beg = c * chunkE, end = min(beg + chunkE, E);
    const int n4 = (end - beg) >> 2;              // beg 4-aligned
    const int4* p = (const int4*)(nodes + beg);
    for (int j = threadIdx.x; j < n4; j += 256) {
        int4 v = p[j];
#pragma unroll
        for (int k = 0; k < 4; ++k) {
            int a = (&v.x)[k] - lo;
            if ((unsigned)a < (unsigned)(4 * B)) {
                int h2 = (a >= 2 * B);
                int r2 = a - (h2 ? 2 * B : 0);
                int h1 = (r2 >= B);
                int bin = r2 - (h1 ? B : 0);
                atomicAdd(&hist[bin], 1u << (((h2 << 1) | h1) << 3));
            }
        }
    }
    for (int j = beg + (n4 << 2) + threadIdx.x; j < end; j += 256) {
        int a = nodes[j] - lo;
        if ((unsigned)a < (unsigned)(4 * B)) {
            int h2 = (a >= 2 * B);
            int r2 = a - (h2 ? 2 * B : 0);
            int h1 = (r2 >= B);
            int bin = r2 - (h1 ? B : 0);
            atomicAdd(&hist[bin], 1u << (((h2 << 1) | h1) << 3));
        }
    }
    __syncthreads();
    unsigned* outp = partial + (size_t)(q * CHK + c) * B;
    for (int b = threadIdx.x; b < B; b += 256) outp[b] = hist[b];
}

// ---- bucketize: ballot-ranked append of packed (bin<<17)|src ----
__global__ __launch_bounds__(256) void k_bucket(const int* __restrict__ src,
                                                const int* __restrict__ dst,
                                                const unsigned* __restrict__ segBase,
                                                unsigned* __restrict__ ebuf,
                                                int E, int B, int chunkEb) {
    __shared__ unsigned lcnt[NRANGE];
    const int c = blockIdx.x;
    const int lane = threadIdx.x & 63;
    if (threadIdx.x < NRANGE) lcnt[threadIdx.x] = 0u;
    __syncthreads();

    unsigned sb[NRANGE];
#pragma unroll
    for (int r = 0; r < NRANGE; ++r) sb[r] = segBase[r * CB + c];

    const int beg = c * chunkEb, end = min(beg + chunkEb, E);
    for (int i = beg + (int)threadIdx.x; i < end; i += 256) {
        int d = dst[i];
        int s = src[i];
        int r = d / B;
        unsigned pk = ((unsigned)(d - r * B) << 17) | (unsigned)s;
#pragma unroll
        for (int rr = 0; rr < NRANGE; ++rr) {
            unsigned long long m = __ballot(r == rr);
            if (m) {
                int leader = __ffsll((long long)m) - 1;
                unsigned base = 0;
                if (lane == leader) base = atomicAdd(&lcnt[rr], (unsigned)__popcll(m));
                base = (unsigned)__shfl((int)base, leader);
                if (r == rr) {
                    unsigned before = (unsigned)__popcll(m & ((1ull << lane) - 1ull));
                    ebuf[sb[rr] + base + before] = pk;
                }
            }
        }
    }
}

// ---- reduce_norm, role-split + ATOMIC WINDOW OFFSETS ----
// tasks 0..NQUAD*Bpad-1: d-role (scan partial_d -> deg/norm_d/offsets)
// tasks NQUAD*Bpad..2*NQUAD*Bpad-1: s-role (sum partial_s -> norm_s)
__global__ __launch_bounds__(256) void k_reduce_norm(const unsigned* __restrict__ partial_s,
                                                     unsigned* __restrict__ partial_d,
                                                     float* __restrict__ norm_s,
                                                     float* __restrict__ norm_d,
                                                     unsigned* __restrict__ deg_d,
                                                     unsigned* __restrict__ offsets,
                                                     unsigned* __restrict__ rangeCur,
                                                     int N, int B, int Bpad) {
    int t = blockIdx.x * 256 + threadIdx.x;
    int lane = threadIdx.x & 63;
    const int half = NQUAD * Bpad;                // multiple of 64
    if (t < half) {                               // ---- d-role ----
        int q = t / Bpad, b = t - q * Bpad;
        bool valid = (b < B);
        unsigned run = 0;
        if (valid) {
            size_t base = (size_t)(q * CHK) * B + b;
            unsigned acc = 0;
            for (int c = 0; c < CHK; ++c) {
                size_t ix = base + (size_t)c * B;
                unsigned v = partial_d[ix];
                partial_d[ix] = acc;              // packed exclusive prefix
                acc += v;
            }
            run = acc;
        }
#pragma unroll
        for (int j = 0; j < 4; ++j) {
            unsigned d1 = valid ? ((run >> (8 * j)) & 0xffu) : 0u;
            unsigned p = d1;                      // inclusive wave scan
#pragma unroll
            for (int off = 1; off < 64; off <<= 1) {
                unsigned o = (unsigned)__shfl_up((int)p, off);
                if (lane >= off) p += o;
            }
            unsigned tot = (unsigned)__shfl((int)p, 63);
            int r = q * 4 + j;                    // wave-uniform
            unsigned wbase = 0;
            if (lane == 63 && tot) wbase = atomicAdd(&rangeCur[r], tot);
            wbase = (unsigned)__shfl((int)wbase, 63);
            if (valid) {
                int n = q * 4 * B + j * B + b;
                if (n < N) {
                    deg_d[n] = d1;
                    norm_d[n] = d1 ? rsqrtf((float)d1) : 0.0f;
                    offsets[n] = wbase + (p - d1);
                }
            }
        }
    } else {                                      // ---- s-role ----
        t -= half;
        int q = t / Bpad, b = t - q * Bpad;
        if (q >= NQUAD || b >= B) return;
        size_t base = (size_t)(q * CHK) * B + b;
        unsigned ds = 0;
        for (int c = 0; c < CHK; ++c) ds += partial_s[base + (size_t)c * B];
#pragma unroll
        for (int j = 0; j < 4; ++j) {
            int n = q * 4 * B + j * B + b;
            if (n < N) {
                unsigned d0 = (ds >> (8 * j)) & 0xffu;
                norm_s[n] = d0 ? rsqrtf((float)d0) : 0.0f;
            }
        }
    }
}

// ---- fill: block (r,ch) reads its contiguous packed ebuf span; LDS cursors ----
__global__ __launch_bounds__(256) void k_fill2(const unsigned* __restrict__ ebuf,
                                               const unsigned* __restrict__ segBase,
                                               const unsigned* __restrict__ offsets,
                                               const unsigned* __restrict__ rel,
                                               unsigned* __restrict__ csr,
                                               int N, int B) {
    extern __shared__ unsigned curs[];
    const int r = blockIdx.x & (NRANGE - 1);
    const int ch = blockIdx.x >> 3;
    const int lo = r * B;
    const int bins = min(B, N - lo);
    const int sh = (r & 3) << 3;
    const unsigned* relp = rel + (size_t)((r >> 2) * CHK + ch) * B;
    for (int b = threadIdx.x; b < bins; b += 256)
        curs[b] = offsets[lo + b] + ((relp[b] >> sh) & 0xffu);
    __syncthreads();

    const unsigned s0 = segBase[r * CB + ch * RB];
    const unsigned s1 = segBase[r * CB + ch * RB + RB];
    for (unsigned i = s0 + threadIdx.x; i < s1; i += 256) {
        unsigned e = ebuf[i];
        unsigned bin = e >> 17;
        if (bin < (unsigned)bins)
            csr[atomicAdd(&curs[bin], 1u)] = e & 0x1ffffu;
    }
}

// h1h = fp16( (x * ns[:,None]) @ W1 )  via MFMA 16x16x32_f16.
__global__ __launch_bounds__(256) void k_gemm1(const float* __restrict__ x,
                                               const _Float16* __restrict__ wt,
                                               const float* __restrict__ norm_s,
                                               __half* __restrict__ h1h, int N) {
    __shared__ __align__(16) _Float16 xs[64 * 128];
    const int tid = threadIdx.x, lane = tid & 63, wv = tid >> 6;
    const int r0 = blockIdx.x * 64;

    f16x8 bf[4][4];
#pragma unroll
    for (int kt = 0; kt < 4; ++kt)
#pragma unroll
        for (int nt = 0; nt < 4; ++nt)
            bf[kt][nt] = *(const f16x8*)&wt[(nt * 16 + (lane & 15)) * 128 +
                                            kt * 32 + (lane >> 4) * 8];

#pragma unroll
    for (int it = 0; it < 8; ++it) {
        int e = it * 256 + tid;
        int r = e >> 5, c = e & 31;
        int row = r0 + r;
        float4 v = (row < N) ? ((const float4*)x)[(size_t)row * 32 + c]
                             : make_float4(0.f, 0.f, 0.f, 0.f);
        __half2 lo2 = __floats2half2_rn(v.x, v.y);
        __half2 hi2 = __floats2half2_rn(v.z, v.w);
        uint2 pk;
        pk.x = *(unsigned*)&lo2;
        pk.y = *(unsigned*)&hi2;
        int byte = r * 256 + c * 8;
        byte ^= (r & 7) << 4;
        *(uint2*)((char*)xs + byte) = pk;
    }
    __syncthreads();

    f32x4 acc[4] = {};
    const int rloc = wv * 16 + (lane & 15);
#pragma unroll
    for (int kt = 0; kt < 4; ++kt) {
        int byte = rloc * 256 + (kt * 32 + (lane >> 4) * 8) * 2;
        byte ^= (rloc & 7) << 4;
        f16x8 af = *(const f16x8*)((char*)xs + byte);
#pragma unroll
        for (int nt = 0; nt < 4; ++nt)
            acc[nt] = __builtin_amdgcn_mfma_f32_16x16x32_f16(af, bf[kt][nt], acc[nt], 0, 0, 0);
    }

#pragma unroll
    for (int j = 0; j < 4; ++j) {
        int row = r0 + wv * 16 + (lane >> 4) * 4 + j;
        if (row < N) {
            float ns = norm_s[row];
#pragma unroll
            for (int nt = 0; nt < 4; ++nt)
                h1h[(size_t)row * 64 + nt * 16 + (lane & 15)] =
                    __float2half(acc[nt][j] * ns);
        }
    }
}

// One wave per node; uint2/lane gathers: 16 lanes/edge (4 ch each), 4 edges
// per instruction, up to 8 loads = 32 edges in flight.
__global__ __launch_bounds__(256) void k_agg_rdot(const unsigned* __restrict__ offsets,
                                                  const unsigned* __restrict__ deg_d,
                                                  const unsigned* __restrict__ csr,
                                                  const __half* __restrict__ h1h,
                                                  const float* __restrict__ norm_s,
                                                  const float* __restrict__ norm_d,
                                                  const float* __restrict__ b1,
                                                  const float* __restrict__ w2l,
                                                  float* __restrict__ s_node, int N) {
    const int lane = threadIdx.x & 63;
    const int slot = lane >> 4;
    const int p = lane & 15;
    const int v = (blockIdx.x * 256 + threadIdx.x) >> 6;
    if (v >= N) return;
    const unsigned beg = offsets[v];
    const unsigned end = beg + deg_d[v];

    float a0 = 0.f, a1 = 0.f, a2 = 0.f, a3 = 0.f;
#define GATHER(sreg) { \
        uint2 u = *(const uint2*)&h1h[(size_t)(sreg) * 64 + 4 * p]; \
        float2 f0 = __half22float2(*(__half2*)&u.x); \
        float2 f1 = __half22float2(*(__half2*)&u.y); \
        a0 += f0.x; a1 += f0.y; a2 += f1.x; a3 += f1.y; }

    for (unsigned base = beg; base < end; base += WAVE) {
        const int n = (int)min((unsigned)WAVE, end - base);
        int sv = (lane < n) ? (int)csr[base + lane] : 0;
        int i = 0;
        for (; i + 32 <= n; i += 32) {
            int s0 = __shfl(sv, i + 0 + slot);
            int s1 = __shfl(sv, i + 4 + slot);
            int s2 = __shfl(sv, i + 8 + slot);
            int s3 = __shfl(sv, i + 12 + slot);
            int s4 = __shfl(sv, i + 16 + slot);
            int s5 = __shfl(sv, i + 20 + slot);
            int s6 = __shfl(sv, i + 24 + slot);
            int s7 = __shfl(sv, i + 28 + slot);
            GATHER(s0); GATHER(s1); GATHER(s2); GATHER(s3);
            GATHER(s4); GATHER(s5); GATHER(s6); GATHER(s7);
        }
        for (; i + 16 <= n; i += 16) {
            int s0 = __shfl(sv, i + 0 + slot);
            int s1 = __shfl(sv, i + 4 + slot);
            int s2 = __shfl(sv, i + 8 + slot);
            int s3 = __shfl(sv, i + 12 + slot);
            GATHER(s0); GATHER(s1); GATHER(s2); GATHER(s3);
        }
        for (; i < n; i += 4) {
            int e = i + slot;
            int s = __shfl(sv, min(e, n - 1));
            if (e < n) GATHER(s);
        }
    }
#undef GATHER
    a0 += __shfl_xor(a0, 16); a0 += __shfl_xor(a0, 32);
    a1 += __shfl_xor(a1, 16); a1 += __shfl_xor(a1, 32);
    a2 += __shfl_xor(a2, 16); a2 += __shfl_xor(a2, 32);
    a3 += __shfl_xor(a3, 16); a3 += __shfl_xor(a3, 32);

    float nd = norm_d[v];
    float4 bq = *(const float4*)&b1[4 * p];
    float4 wq = *(const float4*)&w2l[4 * p];
    float t = fmaxf(fmaf(a0, nd, bq.x), 0.f) * wq.x
            + fmaxf(fmaf(a1, nd, bq.y), 0.f) * wq.y
            + fmaxf(fmaf(a2, nd, bq.z), 0.f) * wq.z
            + fmaxf(fmaf(a3, nd, bq.w), 0.f) * wq.w;
#pragma unroll
    for (int off = 8; off; off >>= 1) t += __shfl_xor(t, off);
    if (lane == 0) s_node[v] = t * norm_s[v];
}

// out[v] = nd[v] * sum_{in-edges} s_node[src] + c0 — 4 lanes per node
__global__ __launch_bounds__(256) void k_out(const unsigned* __restrict__ offsets,
                                             const unsigned* __restrict__ deg_d,
                                             const unsigned* __restrict__ csr,
                                             const float* __restrict__ s_node,
                                             const float* __restrict__ norm_d,
                                             const float* __restrict__ c0,
                                             float* __restrict__ out, int N) {
    int t = blockIdx.x * 256 + threadIdx.x;
    int v = t >> 2, slot = t & 3;
    if (v >= N) return;
    unsigned beg = offsets[v], end = beg + deg_d[v];
    float sum = 0.f;
    for (unsigned j = beg + slot; j < end; j += 4)
        sum += s_node[csr[j]];
    sum += __shfl_xor(sum, 1);
    sum += __shfl_xor(sum, 2);
    if (slot == 0) out[v] = fmaf(sum, norm_d[v], *c0);
}

extern "C" void kernel_launch(void* const* d_in, const int* in_sizes, int n_in,
                              void* d_out, int out_size, void* d_ws, size_t ws_size,
                              hipStream_t stream) {
    const float* x  = (const float*)d_in[0];
    const int*   ei = (const int*)d_in[1];
    const float* W1 = (const float*)d_in[2];
    const float* b1 = (const float*)d_in[3];
    const float* W2 = (const float*)d_in[4];
    const float* b2 = (const float*)d_in[5];
    const float* Wl = (const float*)d_in[6];
    const float* bl = (const float*)d_in[7];

    const int N = in_sizes[0] / 128;
    const int E = in_sizes[1] / 2;
    const int* src = ei;
    const int* dst = ei + E;
    const int B = (N + NRANGE - 1) / NRANGE;        // 12500
    const int Bpad = ((B + 63) / 64) * 64;          // wave-uniform mapping
    const int SLOT = E / NRANGE + 16384;            // per-range csr window
    const int chunkEb = (E + CB - 1) / CB;
    const int chunkE = chunkEb * RB;                // hist chunk, %4==0

    char* w = (char*)d_ws;
    auto alloc = [&](size_t bytes) -> void* {
        void* r = (void*)w;
        w += (bytes + 255) & ~(size_t)255;
        return r;
    };
    float*    norm_s    = (float*)alloc((size_t)N * 4);
    float*    norm_d    = (float*)alloc((size_t)N * 4);
    unsigned* deg_d     = (unsigned*)alloc((size_t)N * 4);
    unsigned* offsets   = (unsigned*)alloc((size_t)N * 4);
    __half*   h1h       = (__half*)alloc((size_t)N * 64 * 2);
    unsigned* csr       = (unsigned*)alloc((size_t)NRANGE * SLOT * 4);
    float*    s_node    = (float*)alloc((size_t)N * 4);
    float*    w2l       = (float*)alloc(64 * 4);
    float*    c0        = (float*)alloc(4);
    _Float16* wt        = (_Float16*)alloc(64 * 128 * 2);
    unsigned* ebuf      = (unsigned*)alloc((size_t)E * 4);
    unsigned* cnt       = (unsigned*)alloc((size_t)(NRANGE * CB + 1) * 4);
    unsigned* segBase   = (unsigned*)alloc((size_t)(NRANGE * CB + 1) * 4);
    unsigned* rangeCur  = (unsigned*)alloc(NRANGE * 4);
    unsigned* partial_s = (unsigned*)alloc((size_t)NQUAD * CHK * B * 4);
    unsigned* partial_d = (unsigned*)alloc((size_t)NQUAD * CHK * B * 4);

    float* out = (float*)d_out;
    const size_t ldsB = (size_t)B * 4;

    k_cnt<<<CB + 1, 256, 0, stream>>>(dst, cnt, E, B, chunkEb,
                                      W1, W2, b2, Wl, bl, wt, w2l, c0);
    k_scancnt2<<<1, 256, 0, stream>>>(cnt, segBase, rangeCur, SLOT);
    k_hist<<<dim3(NQUAD * CHK, 2), 256, ldsB, stream>>>(src, dst, partial_s,
                                                        partial_d, E, B, chunkE);
    k_bucket<<<CB, 256, 0, stream>>>(src, dst, segBase, ebuf, E, B, chunkEb);

    k_reduce_norm<<<(2 * NQUAD * Bpad + 255) / 256, 256, 0, stream>>>(
        partial_s, partial_d, norm_s, norm_d, deg_d, offsets, rangeCur,
        N, B, Bpad);

    k_gemm1<<<(N + 63) / 64, 256, 0, stream>>>(x, wt, norm_s, h1h, N);

    k_fill2<<<NRANGE * CHK, 256, ldsB, stream>>>(ebuf, segBase, offsets,
                                                 partial_d, csr, N, B);

    k_agg_rdot<<<(N + 3) / 4, 256, 0, stream>>>(offsets, deg_d, csr, h1h,
                                                norm_s, norm_d, b1, w2l,
                                                s_node, N);
    k_out<<<(4 * N + 255) / 256, 256, 0, stream>>>(offsets, deg_d, csr, s_node,
                                                   norm_d, c0, out, N);
}